// Round 1
// baseline (397.927 us; speedup 1.0000x reference)
//
#include <hip/hip_runtime.h>
#include <hip/hip_bf16.h>

#define NB 4
#define NH 16
#define NS 2048
#define ND 64
#define QBLK 64
#define KVBLK 64

typedef __attribute__((ext_vector_type(4))) float f32x4;
typedef __attribute__((ext_vector_type(8))) short bf16x8;
typedef __attribute__((ext_vector_type(4))) short bf16x4;

__device__ __forceinline__ unsigned short f2bf(float x) {
    // round-to-nearest-even fp32 -> bf16 (no NaN handling needed here)
    unsigned u = __float_as_uint(x);
    unsigned r = (u + 0x7fffu + ((u >> 16) & 1u)) >> 16;
    return (unsigned short)r;
}

__global__ __launch_bounds__(256) void sdpa_fwd_kernel(
    const float* __restrict__ Qg, const float* __restrict__ Kg,
    const float* __restrict__ Vg, const float* __restrict__ Mg,
    float* __restrict__ Og)
{
    const int tid  = threadIdx.x;
    const int lane = tid & 63;
    const int wid  = tid >> 6;      // wave 0..3
    const int g    = lane >> 4;     // 0..3
    const int c    = lane & 15;     // 0..15

    const int qt = blockIdx.x;      // 0..31 : Q tile of 64 rows
    const int bh = blockIdx.y;      // 0..63 : fused batch*head
    const int b  = bh >> 4;

    // LDS: K tile (swizzled row-major), V^T tile (swizzled), per-wave P, bias
    __shared__ char Kl[KVBLK * ND * 2];          // 8 KB
    __shared__ char Vl[ND * KVBLK * 2];          // 8 KB (transposed: [d][k])
    __shared__ char Pl_all[4 * 16 * KVBLK * 2];  // 8 KB (per-wave 16x64)
    __shared__ float biasl[KVBLK];
    char* Pl = Pl_all + wid * (16 * KVBLK * 2);

    const long bh_base = (long)bh * NS * ND;

    // ---- Q fragments: scale folded in (1/sqrt(D) * log2(e)), bf16 ----
    const float QSCALE = 0.125f * 1.44269504088896340736f;
    bf16x8 qfrag[2];
    {
        const float* qp = Qg + bh_base + (long)(qt * QBLK + wid * 16 + c) * ND;
        #pragma unroll
        for (int kk = 0; kk < 2; ++kk) {
            f32x4 f0 = *(const f32x4*)(qp + kk * 32 + g * 8);
            f32x4 f1 = *(const f32x4*)(qp + kk * 32 + g * 8 + 4);
            bf16x8 q;
            q[0] = (short)f2bf(f0[0] * QSCALE);
            q[1] = (short)f2bf(f0[1] * QSCALE);
            q[2] = (short)f2bf(f0[2] * QSCALE);
            q[3] = (short)f2bf(f0[3] * QSCALE);
            q[4] = (short)f2bf(f1[0] * QSCALE);
            q[5] = (short)f2bf(f1[1] * QSCALE);
            q[6] = (short)f2bf(f1[2] * QSCALE);
            q[7] = (short)f2bf(f1[3] * QSCALE);
            qfrag[kk] = q;
        }
    }

    // online softmax state: lane owns rows (g*4 + r), cols (dg*16 + c)
    float mrow[4], lrow[4];
    f32x4 oacc[4];
    #pragma unroll
    for (int r = 0; r < 4; ++r) { mrow[r] = -1e30f; lrow[r] = 0.0f; }
    #pragma unroll
    for (int dg = 0; dg < 4; ++dg) oacc[dg] = (f32x4){0.f, 0.f, 0.f, 0.f};

    for (int kv0 = 0; kv0 < NS; kv0 += KVBLK) {
        // ---- stage K tile: rows 0..63 of K, bf16, XOR-swizzled ----
        #pragma unroll
        for (int i = 0; i < 4; ++i) {
            int cc = tid + i * 256;           // 0..1023 chunk of 4 floats
            int row = cc >> 4, c4 = cc & 15;
            f32x4 f = *(const f32x4*)(Kg + bh_base + (long)(kv0 + row) * ND + c4 * 4);
            bf16x4 h;
            h[0] = (short)f2bf(f[0]); h[1] = (short)f2bf(f[1]);
            h[2] = (short)f2bf(f[2]); h[3] = (short)f2bf(f[3]);
            *(bf16x4*)(Kl + ((row * 128 + c4 * 8) ^ ((row & 7) << 4))) = h;
        }
        // ---- stage V transposed: Vl[d][k], bf16, XOR-swizzled ----
        #pragma unroll
        for (int i = 0; i < 4; ++i) {
            int cc = tid + i * 256;
            int k = cc >> 4, c4 = cc & 15;
            f32x4 f = *(const f32x4*)(Vg + bh_base + (long)(kv0 + k) * ND + c4 * 4);
            #pragma unroll
            for (int j = 0; j < 4; ++j) {
                int d = c4 * 4 + j;
                *(unsigned short*)(Vl + ((d * 128 + k * 2) ^ ((d & 7) << 4))) = f2bf(f[j]);
            }
        }
        // ---- bias from mask (log2 domain) ----
        if (tid < KVBLK) {
            float mv = Mg[(long)b * NS + kv0 + tid];
            float bn = (1.0f - mv) * -3.4028234663852886e38f;  // 0 or NEG_MIN
            biasl[tid] = bn * 1.44269504088896340736f;
        }
        __syncthreads();

        // ---- S = Q K^T  (4 tiles of 16 cols) ----
        f32x4 st[4];
        #pragma unroll
        for (int t = 0; t < 4; ++t) {
            int key = t * 16 + c;
            int sw = (key & 7) << 4;
            bf16x8 kb0 = *(const bf16x8*)(Kl + ((key * 128 + g * 16) ^ sw));
            bf16x8 kb1 = *(const bf16x8*)(Kl + ((key * 128 + 64 + g * 16) ^ sw));
            f32x4 acc = (f32x4){0.f, 0.f, 0.f, 0.f};
            acc = __builtin_amdgcn_mfma_f32_16x16x32_bf16(qfrag[0], kb0, acc, 0, 0, 0);
            acc = __builtin_amdgcn_mfma_f32_16x16x32_bf16(qfrag[1], kb1, acc, 0, 0, 0);
            float bias = biasl[t * 16 + c];
            #pragma unroll
            for (int r = 0; r < 4; ++r) acc[r] += bias;
            st[t] = acc;
        }

        // ---- online softmax (rows live in 16-lane low-bit groups) ----
        float tmax[4];
        #pragma unroll
        for (int r = 0; r < 4; ++r)
            tmax[r] = fmaxf(fmaxf(st[0][r], st[1][r]), fmaxf(st[2][r], st[3][r]));
        #pragma unroll
        for (int off = 1; off <= 8; off <<= 1) {
            #pragma unroll
            for (int r = 0; r < 4; ++r)
                tmax[r] = fmaxf(tmax[r], __shfl_xor(tmax[r], off, 64));
        }
        float scl[4];
        #pragma unroll
        for (int r = 0; r < 4; ++r) {
            float mnew = fmaxf(mrow[r], tmax[r]);
            scl[r] = __builtin_amdgcn_exp2f(mrow[r] - mnew);
            mrow[r] = mnew;
        }
        float psum[4] = {0.f, 0.f, 0.f, 0.f};
        unsigned short pb[4][4];
        #pragma unroll
        for (int t = 0; t < 4; ++t) {
            #pragma unroll
            for (int r = 0; r < 4; ++r) {
                float p = __builtin_amdgcn_exp2f(st[t][r] - mrow[r]);
                psum[r] += p;
                pb[t][r] = f2bf(p);
            }
        }
        #pragma unroll
        for (int off = 1; off <= 8; off <<= 1) {
            #pragma unroll
            for (int r = 0; r < 4; ++r)
                psum[r] += __shfl_xor(psum[r], off, 64);
        }
        #pragma unroll
        for (int r = 0; r < 4; ++r) {
            lrow[r] = lrow[r] * scl[r] + psum[r];
            oacc[0][r] *= scl[r]; oacc[1][r] *= scl[r];
            oacc[2][r] *= scl[r]; oacc[3][r] *= scl[r];
        }

        // ---- write P (bf16) to per-wave LDS, swizzled ----
        #pragma unroll
        for (int t = 0; t < 4; ++t) {
            #pragma unroll
            for (int r = 0; r < 4; ++r) {
                int row = g * 4 + r;
                *(unsigned short*)(Pl + ((row * 128 + (t * 16 + c) * 2) ^ ((row & 7) << 4))) = pb[t][r];
            }
        }
        // wave-internal LDS write->read fence (per-wave P buffer, no block barrier)
        asm volatile("s_waitcnt lgkmcnt(0)" ::: "memory");
        __builtin_amdgcn_sched_barrier(0);

        // ---- O += P V ----
        {
            int swp = (c & 7) << 4;
            bf16x8 pa0 = *(const bf16x8*)(Pl + ((c * 128 + g * 16) ^ swp));
            bf16x8 pa1 = *(const bf16x8*)(Pl + ((c * 128 + 64 + g * 16) ^ swp));
            #pragma unroll
            for (int dg = 0; dg < 4; ++dg) {
                int d = dg * 16 + c;
                int swv = (d & 7) << 4;
                bf16x8 vb0 = *(const bf16x8*)(Vl + ((d * 128 + g * 16) ^ swv));
                bf16x8 vb1 = *(const bf16x8*)(Vl + ((d * 128 + 64 + g * 16) ^ swv));
                oacc[dg] = __builtin_amdgcn_mfma_f32_16x16x32_bf16(pa0, vb0, oacc[dg], 0, 0, 0);
                oacc[dg] = __builtin_amdgcn_mfma_f32_16x16x32_bf16(pa1, vb1, oacc[dg], 0, 0, 0);
            }
        }
        __syncthreads();
    }

    // ---- epilogue: normalize and store fp32 ----
    #pragma unroll
    for (int r = 0; r < 4; ++r) {
        float inv = 1.0f / lrow[r];
        long qrow = (long)(qt * QBLK + wid * 16 + g * 4 + r);
        float* op = Og + bh_base + qrow * ND;
        #pragma unroll
        for (int dg = 0; dg < 4; ++dg)
            op[dg * 16 + c] = oacc[dg][r] * inv;
    }
}

extern "C" void kernel_launch(void* const* d_in, const int* in_sizes, int n_in,
                              void* d_out, int out_size, void* d_ws, size_t ws_size,
                              hipStream_t stream) {
    const float* Q = (const float*)d_in[0];
    const float* K = (const float*)d_in[1];
    const float* V = (const float*)d_in[2];
    const float* M = (const float*)d_in[3];
    float* O = (float*)d_out;

    dim3 grid(NS / QBLK, NB * NH);   // 32 x 64
    dim3 block(256);
    sdpa_fwd_kernel<<<grid, block, 0, stream>>>(Q, K, V, M, O);
}

// Round 2
// 285.865 us; speedup vs baseline: 1.3920x; 1.3920x over previous
//
#include <hip/hip_runtime.h>
#include <hip/hip_bf16.h>

#define NB 4
#define NH 16
#define NS 2048
#define ND 64
#define QBLK 128
#define KVBLK 64
#define VSTRIDE 144   // bytes; odd multiple of 16 -> bank-even b128 reads
#define PSTRIDE 144

typedef __attribute__((ext_vector_type(4))) float f32x4;
typedef __attribute__((ext_vector_type(8))) short bf16x8;
typedef __attribute__((ext_vector_type(4))) __bf16 bf16v4;
typedef __attribute__((ext_vector_type(8))) __bf16 bf16v8;

__global__ __launch_bounds__(256, 4) void sdpa_fwd_kernel(
    const float* __restrict__ Qg, const float* __restrict__ Kg,
    const float* __restrict__ Vg, const float* __restrict__ Mg,
    float* __restrict__ Og)
{
    const int tid  = threadIdx.x;
    const int lane = tid & 63;
    const int wid  = tid >> 6;      // wave 0..3
    const int g    = lane >> 4;     // 0..3
    const int c    = lane & 15;     // 0..15

    const int qt = blockIdx.x;      // 0..15 : Q tile of 128 rows
    const int bh = blockIdx.y;      // 0..63
    const int b  = bh >> 4;

    __shared__ char Kl[KVBLK * 128];          // 8 KB, row-major bf16, XOR-swizzled
    __shared__ char Vl[ND * VSTRIDE];         // 9216 B, V^T [d][k] bf16, padded stride
    __shared__ char Pl_all[4 * 32 * PSTRIDE]; // 18432 B, per-wave P [q][k] bf16
    __shared__ float biasl[KVBLK];
    char* Pw = Pl_all + wid * (32 * PSTRIDE);

    const long bh_base = (long)bh * NS * ND;

    // ---- Q fragments (B-operand layout: lane&15 = q, elems = k-dim) ----
    const float QSCALE = 0.125f * 1.44269504088896340736f;  // 1/sqrt(D) * log2(e)
    bf16x8 qfrag[2][2];
    #pragma unroll
    for (int s = 0; s < 2; ++s) {
        const float* qp = Qg + bh_base + (long)(qt * QBLK + wid * 32 + s * 16 + c) * ND;
        #pragma unroll
        for (int kk = 0; kk < 2; ++kk) {
            f32x4 f0 = *(const f32x4*)(qp + kk * 32 + g * 8);
            f32x4 f1 = *(const f32x4*)(qp + kk * 32 + g * 8 + 4);
            bf16v8 q;
            q[0] = (__bf16)(f0[0] * QSCALE); q[1] = (__bf16)(f0[1] * QSCALE);
            q[2] = (__bf16)(f0[2] * QSCALE); q[3] = (__bf16)(f0[3] * QSCALE);
            q[4] = (__bf16)(f1[0] * QSCALE); q[5] = (__bf16)(f1[1] * QSCALE);
            q[6] = (__bf16)(f1[2] * QSCALE); q[7] = (__bf16)(f1[3] * QSCALE);
            qfrag[s][kk] = *(bf16x8*)&q;
        }
    }

    // online-softmax state: lane's stats are for q-row (sub-tile s, row c)
    float mrow[2] = {-1e30f, -1e30f};
    float lrow[2] = {0.0f, 0.0f};
    f32x4 oacc[2][4];
    #pragma unroll
    for (int s = 0; s < 2; ++s)
        #pragma unroll
        for (int dt = 0; dt < 4; ++dt) oacc[s][dt] = (f32x4){0.f, 0.f, 0.f, 0.f};

    const int dl = tid & 63;                     // V-staging: lane owns column d=dl
    const float* vcol = Vg + bh_base + dl;

    for (int kv0 = 0; kv0 < NS; kv0 += KVBLK) {
        // ---- stage K tile rows (bf16, XOR-swizzle) ----
        #pragma unroll
        for (int i = 0; i < 4; ++i) {
            int cc = tid + i * 256;              // 1024 chunks of 4 floats
            int row = cc >> 4, c4 = cc & 15;
            f32x4 f = *(const f32x4*)(Kg + bh_base + (long)(kv0 + row) * ND + c4 * 4);
            bf16v4 h;
            h[0] = (__bf16)f[0]; h[1] = (__bf16)f[1];
            h[2] = (__bf16)f[2]; h[3] = (__bf16)f[3];
            *(bf16v4*)(Kl + ((row * 128 + c4 * 8) ^ ((row & 7) << 4))) = h;
        }
        // ---- stage V^T: lane owns d=dl, loads a k-quad column, b64 write ----
        #pragma unroll
        for (int i = 0; i < 4; ++i) {
            int k0 = (wid + i * 4) * 4;          // 0,16,32,48 + wid*4
            float v0 = vcol[(long)(kv0 + k0 + 0) * ND];
            float v1 = vcol[(long)(kv0 + k0 + 1) * ND];
            float v2 = vcol[(long)(kv0 + k0 + 2) * ND];
            float v3 = vcol[(long)(kv0 + k0 + 3) * ND];
            bf16v4 h;
            h[0] = (__bf16)v0; h[1] = (__bf16)v1; h[2] = (__bf16)v2; h[3] = (__bf16)v3;
            *(bf16v4*)(Vl + dl * VSTRIDE + k0 * 2) = h;
        }
        // ---- bias (log2 domain) ----
        if (tid < KVBLK) {
            float mv = Mg[(long)b * NS + kv0 + tid];
            biasl[tid] = (1.0f - mv) * -3.4028234663852886e38f * 1.44269504088896340736f;
        }
        __syncthreads();

        // ---- S^T = K Q^T : lane holds S[key=t*16+g*4+r][q=c] ----
        f32x4 st[2][4];
        #pragma unroll
        for (int t = 0; t < 4; ++t) {
            int key = t * 16 + c;
            int sw = (key & 7) << 4;
            bf16x8 kb0 = *(const bf16x8*)(Kl + ((key * 128 + g * 16) ^ sw));
            bf16x8 kb1 = *(const bf16x8*)(Kl + ((key * 128 + 64 + g * 16) ^ sw));
            f32x4 bias4 = *(const f32x4*)(biasl + t * 16 + g * 4);
            #pragma unroll
            for (int s = 0; s < 2; ++s) {
                f32x4 acc = (f32x4){0.f, 0.f, 0.f, 0.f};
                acc = __builtin_amdgcn_mfma_f32_16x16x32_bf16(kb0, qfrag[s][0], acc, 0, 0, 0);
                acc = __builtin_amdgcn_mfma_f32_16x16x32_bf16(kb1, qfrag[s][1], acc, 0, 0, 0);
                st[s][t] = acc + bias4;
            }
        }

        // ---- online softmax (row q=c lives across the 4 g-lanes) ----
        #pragma unroll
        for (int s = 0; s < 2; ++s) {
            float tm = st[s][0][0];
            #pragma unroll
            for (int t = 0; t < 4; ++t)
                #pragma unroll
                for (int r = 0; r < 4; ++r) tm = fmaxf(tm, st[s][t][r]);
            tm = fmaxf(tm, __shfl_xor(tm, 16));
            tm = fmaxf(tm, __shfl_xor(tm, 32));
            float mnew = fmaxf(mrow[s], tm);
            float scl = __builtin_amdgcn_exp2f(mrow[s] - mnew);
            mrow[s] = mnew;
            float ps = 0.f;
            #pragma unroll
            for (int t = 0; t < 4; ++t) {
                bf16v4 pb;
                #pragma unroll
                for (int r = 0; r < 4; ++r) {
                    float p = __builtin_amdgcn_exp2f(st[s][t][r] - mnew);
                    ps += p;
                    pb[r] = (__bf16)p;
                }
                *(bf16v4*)(Pw + (s * 16 + c) * PSTRIDE + (t * 16 + g * 4) * 2) = pb;
            }
            ps += __shfl_xor(ps, 16);
            ps += __shfl_xor(ps, 32);
            lrow[s] = lrow[s] * scl + ps;
            #pragma unroll
            for (int r = 0; r < 4; ++r) {
                float sb = __shfl(scl, g * 4 + r);
                #pragma unroll
                for (int dt = 0; dt < 4; ++dt) oacc[s][dt][r] *= sb;
            }
        }

        // wave-internal LDS write->read fence (P is per-wave)
        asm volatile("s_waitcnt lgkmcnt(0)" ::: "memory");
        __builtin_amdgcn_sched_barrier(0);

        // ---- O += P V ----
        bf16x8 pa[2][2];
        #pragma unroll
        for (int s = 0; s < 2; ++s)
            #pragma unroll
            for (int h = 0; h < 2; ++h)
                pa[s][h] = *(const bf16x8*)(Pw + (s * 16 + c) * PSTRIDE + h * 64 + g * 16);
        #pragma unroll
        for (int dt = 0; dt < 4; ++dt) {
            int d = dt * 16 + c;
            bf16x8 vb0 = *(const bf16x8*)(Vl + d * VSTRIDE + g * 16);
            bf16x8 vb1 = *(const bf16x8*)(Vl + d * VSTRIDE + 64 + g * 16);
            #pragma unroll
            for (int s = 0; s < 2; ++s) {
                oacc[s][dt] = __builtin_amdgcn_mfma_f32_16x16x32_bf16(pa[s][0], vb0, oacc[s][dt], 0, 0, 0);
                oacc[s][dt] = __builtin_amdgcn_mfma_f32_16x16x32_bf16(pa[s][1], vb1, oacc[s][dt], 0, 0, 0);
            }
        }
        __syncthreads();
    }

    // ---- epilogue: normalize (broadcast 1/l to oacc rows) and store ----
    #pragma unroll
    for (int s = 0; s < 2; ++s) {
        float inv = 1.0f / lrow[s];
        #pragma unroll
        for (int r = 0; r < 4; ++r) {
            float ib = __shfl(inv, g * 4 + r);
            float* op = Og + bh_base + (long)(qt * QBLK + wid * 32 + s * 16 + g * 4 + r) * ND;
            #pragma unroll
            for (int dt = 0; dt < 4; ++dt)
                op[dt * 16 + c] = oacc[s][dt][r] * ib;
        }
    }
}

extern "C" void kernel_launch(void* const* d_in, const int* in_sizes, int n_in,
                              void* d_out, int out_size, void* d_ws, size_t ws_size,
                              hipStream_t stream) {
    const float* Q = (const float*)d_in[0];
    const float* K = (const float*)d_in[1];
    const float* V = (const float*)d_in[2];
    const float* M = (const float*)d_in[3];
    float* O = (float*)d_out;

    dim3 grid(NS / QBLK, NB * NH);   // 16 x 64 = 1024 blocks
    dim3 block(256);
    sdpa_fwd_kernel<<<grid, block, 0, stream>>>(Q, K, V, M, O);
}